// Round 1
// baseline (260.767 us; speedup 1.0000x reference)
//
#include <hip/hip_runtime.h>

#define L 2048
#define H 8
#define S 128
#define B 8
#define HS 1024

// ---------------- K1: E = exp(W) (transposed to [h][d]), Z = causal prefix sums ----------------
__global__ __launch_bounds__(256) void k1_prep(const float* __restrict__ W,
                                               float* __restrict__ E,
                                               float* __restrict__ Z) {
  const int h = blockIdx.x;
  const int t = threadIdx.x;
  const int d0 = t * 8;
  float e[8];
  float run = 0.f;
#pragma unroll
  for (int k = 0; k < 8; ++k) {
    float v = expf(W[(d0 + k) * H + h]);
    e[k] = v; run += v;
  }
  __shared__ float tot[256];
  tot[t] = run;
  __syncthreads();
  for (int off = 1; off < 256; off <<= 1) {
    float v = (t >= off) ? tot[t - off] : 0.f;
    __syncthreads();
    tot[t] += v;
    __syncthreads();
  }
  float c = (t == 0) ? 0.f : tot[t - 1];
#pragma unroll
  for (int k = 0; k < 8; ++k) {
    c += e[k];
    E[h * L + d0 + k] = e[k];
    Z[h * L + d0 + k] = c;
  }
}

// ---------------- K2: q[b,h*S+s] = (1/Z[L-1,h]) * sum_j E[L-1-j,h] * x[b,j,s] ----------------
__global__ __launch_bounds__(128) void k2_q(const float* __restrict__ x,
                                            const float* __restrict__ E,
                                            const float* __restrict__ Z,
                                            float* __restrict__ q) {
  const int b = blockIdx.x, h = blockIdx.y;
  const int s = threadIdx.x;
  const float* __restrict__ Eh = E + h * L;
  const float* __restrict__ xb = x + (size_t)b * L * S + s;
  float a0 = 0.f, a1 = 0.f, a2 = 0.f, a3 = 0.f;
  for (int j = 0; j < L; j += 4) {
    a0 += Eh[L - 1 - j] * xb[(size_t)(j    ) * S];
    a1 += Eh[L - 2 - j] * xb[(size_t)(j + 1) * S];
    a2 += Eh[L - 3 - j] * xb[(size_t)(j + 2) * S];
    a3 += Eh[L - 4 - j] * xb[(size_t)(j + 3) * S];
  }
  q[(b * H + h) * S + s] = ((a0 + a1) + (a2 + a3)) / Z[h * L + (L - 1)];
}

// ---------------- K3: v[b,e] = sum_d q[b,d] * A[d,e] ----------------
__global__ __launch_bounds__(256) void k3_v(const float* __restrict__ q,
                                            const float* __restrict__ A,
                                            float* __restrict__ v) {
  const int b = blockIdx.x;
  const int e = blockIdx.y * 256 + threadIdx.x;
  __shared__ float ql[HS];
  for (int i = threadIdx.x; i < HS; i += 256) ql[i] = q[b * HS + i];
  __syncthreads();
  float a0 = 0.f, a1 = 0.f, a2 = 0.f, a3 = 0.f;
  for (int d = 0; d < HS; d += 4) {
    a0 += ql[d    ] * A[(size_t)(d    ) * HS + e];
    a1 += ql[d + 1] * A[(size_t)(d + 1) * HS + e];
    a2 += ql[d + 2] * A[(size_t)(d + 2) * HS + e];
    a3 += ql[d + 3] * A[(size_t)(d + 3) * HS + e];
  }
  v[b * HS + e] = (a0 + a1) + (a2 + a3);
}

// ---------------- K4: u[b,h,j] = sum_s v[b,h*S+s] * x[b,j,s]  (zero-padded rows) ----------------
__global__ __launch_bounds__(256) void k4_u(const float* __restrict__ x,
                                            const float* __restrict__ v,
                                            float* __restrict__ u_pad) {
  const int b = blockIdx.x, jc = blockIdx.y;
  const int t = threadIdx.x;
  const int j = jc * 256 + t;
  // zero the pad (front) region of each row
#pragma unroll
  for (int h = 0; h < H; ++h)
    u_pad[(size_t)(b * H + h) * (2 * L) + jc * 256 + t] = 0.f;
  const float4* __restrict__ xr = (const float4*)(x + ((size_t)b * L + j) * S);
  float acc[H];
#pragma unroll
  for (int h = 0; h < H; ++h) acc[h] = 0.f;
  for (int sc = 0; sc < 32; ++sc) {
    float4 xv = xr[sc];
#pragma unroll
    for (int h = 0; h < H; ++h) {
      float4 vv = *(const float4*)(v + b * HS + h * S + sc * 4);  // wave-uniform -> s_load
      acc[h] += xv.x * vv.x + xv.y * vv.y + xv.z * vv.z + xv.w * vv.w;
    }
  }
#pragma unroll
  for (int h = 0; h < H; ++h)
    u_pad[(size_t)(b * H + h) * (2 * L) + L + j] = acc[h];
}

// ---------------- K5: C[b,h,l] = sum_d E[d,h]*u[b,h,l-d]; scores[b,l] = sum_h C/Z[l,h] ----------
// Register-blocked FIR: lane owns 4 consecutive l, slides an 8-float u-window.
__global__ __launch_bounds__(256) void k5_conv(const float* __restrict__ u_pad,
                                               const float* __restrict__ E,
                                               const float* __restrict__ Z,
                                               float* __restrict__ scores) {
  const int b = blockIdx.x;
  const int l0 = blockIdx.y * 128;
  const int t = threadIdx.x;
  const int tsub = t & 31;
  const int h = t >> 5;
  const int Lb = l0 + tsub * 4;
  const float* __restrict__ ur = u_pad + (size_t)(b * H + h) * (2 * L) + L;
  const float4* __restrict__ Eh4 = (const float4*)(E + h * L);
  float acc0 = 0.f, acc1 = 0.f, acc2 = 0.f, acc3 = 0.f;
  const int Dmax = l0 + 128;
  // window w[i] = u[Lb - d0 - 4 + i], i in [0,8): lo = w[0..3], hi = w[4..7]
  float4 lo = *(const float4*)(ur + Lb - 4);
  float4 hi = *(const float4*)(ur + Lb);
  for (int d0 = 0; d0 < Dmax; d0 += 4) {
    float4 ev  = Eh4[d0 >> 2];                          // wave-uniform -> scalar load
    float4 nlo = *(const float4*)(ur + Lb - d0 - 8);    // next window chunk (always in-bounds: pad)
    // d=d0+0: u[Lb+r-d0]   = w[r+4]
    acc0 += ev.x * hi.x; acc1 += ev.x * hi.y; acc2 += ev.x * hi.z; acc3 += ev.x * hi.w;
    // d=d0+1: w[r+3]
    acc0 += ev.y * lo.w; acc1 += ev.y * hi.x; acc2 += ev.y * hi.y; acc3 += ev.y * hi.z;
    // d=d0+2: w[r+2]
    acc0 += ev.z * lo.z; acc1 += ev.z * lo.w; acc2 += ev.z * hi.x; acc3 += ev.z * hi.y;
    // d=d0+3: w[r+1]
    acc0 += ev.w * lo.y; acc1 += ev.w * lo.z; acc2 += ev.w * lo.w; acc3 += ev.w * hi.x;
    hi = lo; lo = nlo;
  }
  __shared__ float sred[H][128];
  const float* __restrict__ Zh = Z + h * L;
  sred[h][tsub * 4 + 0] = acc0 / Zh[Lb + 0];
  sred[h][tsub * 4 + 1] = acc1 / Zh[Lb + 1];
  sred[h][tsub * 4 + 2] = acc2 / Zh[Lb + 2];
  sred[h][tsub * 4 + 3] = acc3 / Zh[Lb + 3];
  __syncthreads();
  if (t < 128) {
    float sc = 0.f;
#pragma unroll
    for (int hh = 0; hh < H; ++hh) sc += sred[hh][t];
    const int l = l0 + t;
    if (l < L - 1) scores[b * L + l] = sc;   // l = L-1 row excluded (keys are X1[:, :-1])
  }
}

// ---------------- K6: w2 = softmax(scores[b, 0:L-1]); out[b,s] = sum_l w2[l]*x[b,l,s] ----------
__global__ __launch_bounds__(256) void k6_out(const float* __restrict__ x,
                                              const float* __restrict__ scores,
                                              float* __restrict__ out) {
  const int b = blockIdx.x;
  const int t = threadIdx.x;
  __shared__ float p[L];
  __shared__ float red[256];
  __shared__ float ored[2][S];
  const float* __restrict__ sc = scores + b * L;
  float mx = -3.4e38f;
  for (int l = t; l < L - 1; l += 256) mx = fmaxf(mx, sc[l]);
  red[t] = mx;
  __syncthreads();
  for (int off = 128; off > 0; off >>= 1) {
    if (t < off) red[t] = fmaxf(red[t], red[t + off]);
    __syncthreads();
  }
  mx = red[0];
  __syncthreads();
  float sm = 0.f;
  for (int l = t; l < L - 1; l += 256) { float e = expf(sc[l] - mx); p[l] = e; sm += e; }
  red[t] = sm;
  __syncthreads();
  for (int off = 128; off > 0; off >>= 1) {
    if (t < off) red[t] += red[t + off];
    __syncthreads();
  }
  const float den = red[0];
  const int s = t & 127, half = t >> 7;
  float acc = 0.f;
  const int lbeg = half ? 1024 : 0;
  const int lend = half ? (L - 1) : 1024;
  for (int l = lbeg; l < lend; ++l)
    acc += p[l] * x[((size_t)b * L + l) * S + s];
  ored[half][s] = acc;
  __syncthreads();
  if (t < S) out[b * S + t] = (ored[0][t] + ored[1][t]) / den;
}

extern "C" void kernel_launch(void* const* d_in, const int* in_sizes, int n_in,
                              void* d_out, int out_size, void* d_ws, size_t ws_size,
                              hipStream_t stream) {
  const float* x = (const float*)d_in[0];   // (B, L, S) f32
  const float* W = (const float*)d_in[1];   // (L, H)   f32
  const float* A = (const float*)d_in[2];   // (HS, HS) f32
  float* out = (float*)d_out;               // (B, S)   f32

  float* ws     = (float*)d_ws;
  float* E      = ws;                        // H*L      = 16384
  float* Z      = E + H * L;                 // H*L      = 16384
  float* q      = Z + H * L;                 // B*HS     =  8192
  float* v      = q + B * HS;                // B*HS     =  8192
  float* u_pad  = v + B * HS;                // B*H*2L   = 262144 (front half zeros)
  float* scores = u_pad + (size_t)B * H * 2 * L;  // B*L = 16384
  // total: 327680 floats = 1.25 MB of d_ws

  k1_prep<<<H, 256, 0, stream>>>(W, E, Z);
  k2_q  <<<dim3(B, H),      128, 0, stream>>>(x, E, Z, q);
  k3_v  <<<dim3(B, HS/256), 256, 0, stream>>>(q, A, v);
  k4_u  <<<dim3(B, L/256),  256, 0, stream>>>(x, v, u_pad);
  k5_conv<<<dim3(B, L/128), 256, 0, stream>>>(u_pad, E, Z, scores);
  k6_out<<<B, 256, 0, stream>>>(x, scores, out);
}

// Round 2
// 166.614 us; speedup vs baseline: 1.5651x; 1.5651x over previous
//
#include <hip/hip_runtime.h>

#define L 2048
#define H 8
#define S 128
#define B 8
#define HS 1024

// ---------------- K1: E = exp(W) (transposed to [h][d]), Z = causal prefix sums ----------------
__global__ __launch_bounds__(256) void k1_prep(const float* __restrict__ W,
                                               float* __restrict__ E,
                                               float* __restrict__ Z) {
  const int h = blockIdx.x;
  const int t = threadIdx.x;
  const int d0 = t * 8;
  float e[8];
  float run = 0.f;
#pragma unroll
  for (int k = 0; k < 8; ++k) {
    float v = expf(W[(d0 + k) * H + h]);
    e[k] = v; run += v;
  }
  __shared__ float tot[256];
  tot[t] = run;
  __syncthreads();
  for (int off = 1; off < 256; off <<= 1) {
    float v = (t >= off) ? tot[t - off] : 0.f;
    __syncthreads();
    tot[t] += v;
    __syncthreads();
  }
  float c = (t == 0) ? 0.f : tot[t - 1];
#pragma unroll
  for (int k = 0; k < 8; ++k) {
    c += e[k];
    E[h * L + d0 + k] = e[k];
    Z[h * L + d0 + k] = c;
  }
}

// ---------------- K2: q[b,h*S+s] = (1/Z[L-1,h]) * sum_j E[L-1-j,h] * x[b,j,s] ----------------
__global__ __launch_bounds__(128) void k2_q(const float* __restrict__ x,
                                            const float* __restrict__ E,
                                            const float* __restrict__ Z,
                                            float* __restrict__ q) {
  const int b = blockIdx.x, h = blockIdx.y;
  const int s = threadIdx.x;
  const float* __restrict__ Eh = E + h * L;
  const float* __restrict__ xb = x + (size_t)b * L * S + s;
  float a0 = 0.f, a1 = 0.f, a2 = 0.f, a3 = 0.f;
  for (int j = 0; j < L; j += 4) {
    a0 += Eh[L - 1 - j] * xb[(size_t)(j    ) * S];
    a1 += Eh[L - 2 - j] * xb[(size_t)(j + 1) * S];
    a2 += Eh[L - 3 - j] * xb[(size_t)(j + 2) * S];
    a3 += Eh[L - 4 - j] * xb[(size_t)(j + 3) * S];
  }
  q[(b * H + h) * S + s] = ((a0 + a1) + (a2 + a3)) / Z[h * L + (L - 1)];
}

// ---------------- K3: v[b,e] = sum_d q[b,d] * A[d,e] ----------------
__global__ __launch_bounds__(256) void k3_v(const float* __restrict__ q,
                                            const float* __restrict__ A,
                                            float* __restrict__ v) {
  const int b = blockIdx.x;
  const int e = blockIdx.y * 256 + threadIdx.x;
  __shared__ float ql[HS];
  for (int i = threadIdx.x; i < HS; i += 256) ql[i] = q[b * HS + i];
  __syncthreads();
  float a0 = 0.f, a1 = 0.f, a2 = 0.f, a3 = 0.f;
  for (int d = 0; d < HS; d += 4) {
    a0 += ql[d    ] * A[(size_t)(d    ) * HS + e];
    a1 += ql[d + 1] * A[(size_t)(d + 1) * HS + e];
    a2 += ql[d + 2] * A[(size_t)(d + 2) * HS + e];
    a3 += ql[d + 3] * A[(size_t)(d + 3) * HS + e];
  }
  v[b * HS + e] = (a0 + a1) + (a2 + a3);
}

// ---------------- K4: u[b,h,j] = sum_s v[b,h*S+s] * x[b,j,s]  (zero-padded rows) ----------------
__global__ __launch_bounds__(256) void k4_u(const float* __restrict__ x,
                                            const float* __restrict__ v,
                                            float* __restrict__ u_pad) {
  const int b = blockIdx.x, jc = blockIdx.y;
  const int t = threadIdx.x;
  const int j = jc * 256 + t;
#pragma unroll
  for (int h = 0; h < H; ++h)
    u_pad[(size_t)(b * H + h) * (2 * L) + jc * 256 + t] = 0.f;
  const float4* __restrict__ xr = (const float4*)(x + ((size_t)b * L + j) * S);
  float acc[H];
#pragma unroll
  for (int h = 0; h < H; ++h) acc[h] = 0.f;
  for (int sc = 0; sc < 32; ++sc) {
    float4 xv = xr[sc];
#pragma unroll
    for (int h = 0; h < H; ++h) {
      float4 vv = *(const float4*)(v + b * HS + h * S + sc * 4);  // wave-uniform -> s_load
      acc[h] += xv.x * vv.x + xv.y * vv.y + xv.z * vv.z + xv.w * vv.w;
    }
  }
#pragma unroll
  for (int h = 0; h < H; ++h)
    u_pad[(size_t)(b * H + h) * (2 * L) + L + j] = acc[h];
}

// ---------------- K5: C[b,h,l] = sum_d E[d,h]*u[b,h,l-d]; scores[b,l] = sum_h C/Z[l,h] ----------
__global__ __launch_bounds__(256) void k5_conv(const float* __restrict__ u_pad,
                                               const float* __restrict__ E,
                                               const float* __restrict__ Z,
                                               float* __restrict__ scores) {
  const int b = blockIdx.x;
  const int l0 = blockIdx.y * 128;
  const int t = threadIdx.x;
  const int tsub = t & 31;
  const int h = t >> 5;
  const int Lb = l0 + tsub * 4;
  const float* __restrict__ ur = u_pad + (size_t)(b * H + h) * (2 * L) + L;
  const float4* __restrict__ Eh4 = (const float4*)(E + h * L);
  float acc0 = 0.f, acc1 = 0.f, acc2 = 0.f, acc3 = 0.f;
  const int Dmax = l0 + 128;
  float4 lo = *(const float4*)(ur + Lb - 4);
  float4 hi = *(const float4*)(ur + Lb);
  for (int d0 = 0; d0 < Dmax; d0 += 4) {
    float4 ev  = Eh4[d0 >> 2];
    float4 nlo = *(const float4*)(ur + Lb - d0 - 8);
    acc0 += ev.x * hi.x; acc1 += ev.x * hi.y; acc2 += ev.x * hi.z; acc3 += ev.x * hi.w;
    acc0 += ev.y * lo.w; acc1 += ev.y * hi.x; acc2 += ev.y * hi.y; acc3 += ev.y * hi.z;
    acc0 += ev.z * lo.z; acc1 += ev.z * lo.w; acc2 += ev.z * hi.x; acc3 += ev.z * hi.y;
    acc0 += ev.w * lo.y; acc1 += ev.w * lo.z; acc2 += ev.w * lo.w; acc3 += ev.w * hi.x;
    hi = lo; lo = nlo;
  }
  __shared__ float sred[H][128];
  const float* __restrict__ Zh = Z + h * L;
  sred[h][tsub * 4 + 0] = acc0 / Zh[Lb + 0];
  sred[h][tsub * 4 + 1] = acc1 / Zh[Lb + 1];
  sred[h][tsub * 4 + 2] = acc2 / Zh[Lb + 2];
  sred[h][tsub * 4 + 3] = acc3 / Zh[Lb + 3];
  __syncthreads();
  if (t < 128) {
    float sc = 0.f;
#pragma unroll
    for (int hh = 0; hh < H; ++hh) sc += sred[hh][t];
    const int l = l0 + t;
    if (l < L - 1) scores[b * L + l] = sc;
  }
}

// ---------------- K6a: e[b,l] = exp(scores - max); den[b] = sum ----------------
__global__ __launch_bounds__(256) void k6a_soft(const float* __restrict__ scores,
                                                float* __restrict__ p,
                                                float* __restrict__ den) {
  const int b = blockIdx.x;
  const int t = threadIdx.x;
  __shared__ float red[256];
  const float* __restrict__ sc = scores + b * L;
  float mx = -3.4e38f;
  for (int l = t; l < L - 1; l += 256) mx = fmaxf(mx, sc[l]);
  red[t] = mx;
  __syncthreads();
  for (int off = 128; off > 0; off >>= 1) {
    if (t < off) red[t] = fmaxf(red[t], red[t + off]);
    __syncthreads();
  }
  mx = red[0];
  __syncthreads();
  float sm = 0.f;
  for (int l = t; l < L - 1; l += 256) {
    float e = expf(sc[l] - mx);
    p[b * L + l] = e;
    sm += e;
  }
  red[t] = sm;
  __syncthreads();
  for (int off = 128; off > 0; off >>= 1) {
    if (t < off) red[t] += red[t + off];
    __syncthreads();
  }
  if (t == 0) {
    den[b] = red[0];
    p[b * L + (L - 1)] = 0.f;   // excluded row; lets K6b loop run full chunks
  }
}

// ---------------- K6b: partial[b,c,s] = sum_{l in chunk c} p[b,l] * x[b,l,s] ----------------
// 32 chunks of 64 rows; 256 threads: s4 = t&31 (float4 col), r = t>>5 (8 row-groups)
__global__ __launch_bounds__(256) void k6b_wsum(const float* __restrict__ x,
                                                const float* __restrict__ p,
                                                float* __restrict__ partial) {
  const int b = blockIdx.x, c = blockIdx.y;
  const int t = threadIdx.x;
  const int s4 = t & 31;
  const int r = t >> 5;
  const int base = c * 64;
  const float4* __restrict__ x4 = (const float4*)(x + (size_t)b * L * S);
  const float* __restrict__ pb = p + b * L;
  float4 acc = {0.f, 0.f, 0.f, 0.f};
#pragma unroll
  for (int k = 0; k < 8; ++k) {
    const int l = base + r + k * 8;
    const float w = pb[l];                       // wave-uniform within 32-lane row group
    const float4 xv = x4[(size_t)l * 32 + s4];   // 16B/lane coalesced
    acc.x += w * xv.x; acc.y += w * xv.y; acc.z += w * xv.z; acc.w += w * xv.w;
  }
  __shared__ float part[8][S];
  part[r][s4 * 4 + 0] = acc.x;
  part[r][s4 * 4 + 1] = acc.y;
  part[r][s4 * 4 + 2] = acc.z;
  part[r][s4 * 4 + 3] = acc.w;
  __syncthreads();
  if (t < S) {
    float sm = 0.f;
#pragma unroll
    for (int rr = 0; rr < 8; ++rr) sm += part[rr][t];
    partial[((size_t)b * 32 + c) * S + t] = sm;
  }
}

// ---------------- K6c: out[b,s] = sum_c partial[b,c,s] / den[b] ----------------
__global__ __launch_bounds__(128) void k6c_final(const float* __restrict__ partial,
                                                 const float* __restrict__ den,
                                                 float* __restrict__ out) {
  const int b = blockIdx.x;
  const int s = threadIdx.x;
  float sm = 0.f;
#pragma unroll
  for (int c = 0; c < 32; ++c) sm += partial[((size_t)b * 32 + c) * S + s];
  out[b * S + s] = sm / den[b];
}

extern "C" void kernel_launch(void* const* d_in, const int* in_sizes, int n_in,
                              void* d_out, int out_size, void* d_ws, size_t ws_size,
                              hipStream_t stream) {
  const float* x = (const float*)d_in[0];   // (B, L, S) f32
  const float* W = (const float*)d_in[1];   // (L, H)   f32
  const float* A = (const float*)d_in[2];   // (HS, HS) f32
  float* out = (float*)d_out;               // (B, S)   f32

  float* ws     = (float*)d_ws;
  float* E      = ws;                              // H*L      = 16384
  float* Z      = E + H * L;                       // H*L      = 16384
  float* q      = Z + H * L;                       // B*HS     =  8192
  float* v      = q + B * HS;                      // B*HS     =  8192
  float* u_pad  = v + B * HS;                      // B*H*2L   = 262144
  float* scores = u_pad + (size_t)B * H * 2 * L;   // B*L      = 16384
  float* p      = scores + B * L;                  // B*L      = 16384
  float* den    = p + B * L;                       // B        =     8
  float* partial= den + 64;                        // B*32*S   = 32768
  // total ≈ 1.44 MB of d_ws

  k1_prep <<<H, 256, 0, stream>>>(W, E, Z);
  k2_q    <<<dim3(B, H),      128, 0, stream>>>(x, E, Z, q);
  k3_v    <<<dim3(B, HS/256), 256, 0, stream>>>(q, A, v);
  k4_u    <<<dim3(B, L/256),  256, 0, stream>>>(x, v, u_pad);
  k5_conv <<<dim3(B, L/128),  256, 0, stream>>>(u_pad, E, Z, scores);
  k6a_soft<<<B, 256, 0, stream>>>(scores, p, den);
  k6b_wsum<<<dim3(B, 32),     256, 0, stream>>>(x, p, partial);
  k6c_final<<<B, 128, 0, stream>>>(partial, den, out);
}

// Round 3
// 80.693 us; speedup vs baseline: 3.2316x; 2.0648x over previous
//
#include <hip/hip_runtime.h>

#define L 2048
#define H 8
#define S 128
#define B 8
#define HS 1024

// ---------------- K1: E = exp(W) (transposed to [h][d]), Z = causal prefix sums ----------------
__global__ __launch_bounds__(256) void k1_prep(const float* __restrict__ W,
                                               float* __restrict__ E,
                                               float* __restrict__ Z) {
  const int h = blockIdx.x;
  const int t = threadIdx.x;
  const int d0 = t * 8;
  float e[8];
  float run = 0.f;
#pragma unroll
  for (int k = 0; k < 8; ++k) {
    float v = expf(W[(d0 + k) * H + h]);
    e[k] = v; run += v;
  }
  __shared__ float tot[256];
  tot[t] = run;
  __syncthreads();
  for (int off = 1; off < 256; off <<= 1) {
    float v = (t >= off) ? tot[t - off] : 0.f;
    __syncthreads();
    tot[t] += v;
    __syncthreads();
  }
  float c = (t == 0) ? 0.f : tot[t - 1];
#pragma unroll
  for (int k = 0; k < 8; ++k) {
    c += e[k];
    E[h * L + d0 + k] = e[k];
    Z[h * L + d0 + k] = c;
  }
}

// ---------------- K2a: partial_q[b,jc,h,s] = sum_{j in chunk} E[L-1-j,h] * x[b,j,s] ------------
// 32 chunks of 64 rows; threads: s4 = t&31 (float4 col), r = t>>5 (8 row-groups of 8)
__global__ __launch_bounds__(256) void k2a_qpart(const float* __restrict__ x,
                                                 const float* __restrict__ E,
                                                 float* __restrict__ partial_q) {
  const int b = blockIdx.x, jc = blockIdx.y;
  const int t = threadIdx.x;
  const int s4 = t & 31;
  const int r = t >> 5;
  const int base = jc * 64;
  const float4* __restrict__ x4 = (const float4*)(x + (size_t)b * L * S);
  float4 acc[H];
#pragma unroll
  for (int h = 0; h < H; ++h) acc[h] = make_float4(0.f, 0.f, 0.f, 0.f);
#pragma unroll
  for (int k = 0; k < 8; ++k) {
    const int l = base + k * 8 + r;
    const float4 xv = x4[(size_t)l * 32 + s4];
#pragma unroll
    for (int h = 0; h < H; ++h) {
      const float w = E[h * L + (L - 1 - l)];
      acc[h].x += w * xv.x; acc[h].y += w * xv.y;
      acc[h].z += w * xv.z; acc[h].w += w * xv.w;
    }
  }
  __shared__ float part[8][H][S];   // [r][h][s]
#pragma unroll
  for (int h = 0; h < H; ++h) {
    part[r][h][s4 * 4 + 0] = acc[h].x;
    part[r][h][s4 * 4 + 1] = acc[h].y;
    part[r][h][s4 * 4 + 2] = acc[h].z;
    part[r][h][s4 * 4 + 3] = acc[h].w;
  }
  __syncthreads();
  // 1024 outputs, 4 per thread
#pragma unroll
  for (int k = 0; k < 4; ++k) {
    const int idx = t + k * 256;        // h*S + s
    const int h = idx >> 7, s = idx & 127;
    float sm = 0.f;
#pragma unroll
    for (int rr = 0; rr < 8; ++rr) sm += part[rr][h][s];
    partial_q[((size_t)b * 32 + jc) * HS + idx] = sm;
  }
}

// ---------------- K2b: q[b,i] = sum_jc partial_q / Z[h,L-1] ----------------
__global__ __launch_bounds__(256) void k2b_qred(const float* __restrict__ partial_q,
                                                const float* __restrict__ Z,
                                                float* __restrict__ q) {
  const int b = blockIdx.x;
  const int t = threadIdx.x;           // float4 index: i = 4t
  const int h = t >> 5;
  float4 acc = make_float4(0.f, 0.f, 0.f, 0.f);
  const float4* __restrict__ pq = (const float4*)(partial_q + (size_t)b * 32 * HS);
#pragma unroll 4
  for (int jc = 0; jc < 32; ++jc) {
    float4 v = pq[jc * (HS / 4) + t];
    acc.x += v.x; acc.y += v.y; acc.z += v.z; acc.w += v.w;
  }
  const float inv = 1.f / Z[h * L + (L - 1)];
  float4 o = make_float4(acc.x * inv, acc.y * inv, acc.z * inv, acc.w * inv);
  ((float4*)(q + (size_t)b * HS))[t] = o;
}

// ---------------- K3a: partial_v[b,dc,e] = sum_{d in chunk} q[b,d] * A[d,e] ----------------
__global__ __launch_bounds__(256) void k3a_vpart(const float* __restrict__ q,
                                                 const float* __restrict__ A,
                                                 float* __restrict__ partial_v) {
  const int b = blockIdx.x;
  const int e = blockIdx.y * 256 + threadIdx.x;
  const int dbase = blockIdx.z * 256;
  __shared__ float ql[256];
  ql[threadIdx.x] = q[b * HS + dbase + threadIdx.x];
  __syncthreads();
  float a0 = 0.f, a1 = 0.f, a2 = 0.f, a3 = 0.f;
#pragma unroll 4
  for (int d = 0; d < 256; d += 4) {
    a0 += ql[d    ] * A[(size_t)(dbase + d    ) * HS + e];
    a1 += ql[d + 1] * A[(size_t)(dbase + d + 1) * HS + e];
    a2 += ql[d + 2] * A[(size_t)(dbase + d + 2) * HS + e];
    a3 += ql[d + 3] * A[(size_t)(dbase + d + 3) * HS + e];
  }
  partial_v[((size_t)b * 4 + blockIdx.z) * HS + e] = (a0 + a1) + (a2 + a3);
}

// ---------------- K3b: v[b,e] = sum_dc partial_v ----------------
__global__ __launch_bounds__(256) void k3b_vred(const float* __restrict__ partial_v,
                                                float* __restrict__ v) {
  const int b = blockIdx.x;
  const int t = threadIdx.x;           // float4 index
  const float4* __restrict__ pv = (const float4*)(partial_v + (size_t)b * 4 * HS);
  float4 acc = make_float4(0.f, 0.f, 0.f, 0.f);
#pragma unroll
  for (int dc = 0; dc < 4; ++dc) {
    float4 w = pv[dc * (HS / 4) + t];
    acc.x += w.x; acc.y += w.y; acc.z += w.z; acc.w += w.w;
  }
  ((float4*)(v + (size_t)b * HS))[t] = acc;
}

// ---------------- K4: u[b,h,j] = sum_s v[b,h*S+s] * x[b,j,s]  (zero-padded rows) ----------------
__global__ __launch_bounds__(64) void k4_u(const float* __restrict__ x,
                                           const float* __restrict__ v,
                                           float* __restrict__ u_pad) {
  const int b = blockIdx.x, jc = blockIdx.y;   // 32 chunks of 64
  const int t = threadIdx.x;
  const int j = jc * 64 + t;
#pragma unroll
  for (int h = 0; h < H; ++h)
    u_pad[(size_t)(b * H + h) * (2 * L) + jc * 64 + t] = 0.f;
  const float4* __restrict__ xr = (const float4*)(x + ((size_t)b * L + j) * S);
  float acc[H];
#pragma unroll
  for (int h = 0; h < H; ++h) acc[h] = 0.f;
  for (int sc = 0; sc < 32; ++sc) {
    float4 xv = xr[sc];
#pragma unroll
    for (int h = 0; h < H; ++h) {
      float4 vv = *(const float4*)(v + b * HS + h * S + sc * 4);  // wave-uniform -> s_load
      acc[h] += xv.x * vv.x + xv.y * vv.y + xv.z * vv.z + xv.w * vv.w;
    }
  }
#pragma unroll
  for (int h = 0; h < H; ++h)
    u_pad[(size_t)(b * H + h) * (2 * L) + L + j] = acc[h];
}

// ---------------- K5: partial_s[b,dt,l] = sum_h (1/Z[l,h]) sum_{d in dt-tile} E[d,h]*u[b,h,l-d] -
// 128x128 (l,d) tiles; lane owns 4 consecutive l, slides an 8-float u-window.
__global__ __launch_bounds__(256) void k5_conv(const float* __restrict__ u_pad,
                                               const float* __restrict__ E,
                                               const float* __restrict__ Z,
                                               float* __restrict__ partial_s) {
  const int lt = blockIdx.y, dt = blockIdx.z;
  if (dt > lt) return;
  const int b = blockIdx.x;
  const int l0 = lt * 128;
  const int dbase = dt * 128;
  const int t = threadIdx.x;
  const int tsub = t & 31;
  const int h = t >> 5;
  const int Lb = l0 + tsub * 4;
  const float* __restrict__ ur = u_pad + (size_t)(b * H + h) * (2 * L) + L;
  const float4* __restrict__ Eh4 = (const float4*)(E + h * L);
  float acc0 = 0.f, acc1 = 0.f, acc2 = 0.f, acc3 = 0.f;
  // window w[i] = u[Lb - d0 - 4 + i]: lo = w[0..3], hi = w[4..7]
  float4 lo = *(const float4*)(ur + Lb - dbase - 4);
  float4 hi = *(const float4*)(ur + Lb - dbase);
#pragma unroll 4
  for (int dd = 0; dd < 128; dd += 4) {
    const int d0 = dbase + dd;
    float4 ev  = Eh4[d0 >> 2];                        // wave-uniform -> scalar load
    float4 nlo = *(const float4*)(ur + Lb - d0 - 8);  // in-bounds: zero pad
    acc0 += ev.x * hi.x; acc1 += ev.x * hi.y; acc2 += ev.x * hi.z; acc3 += ev.x * hi.w;
    acc0 += ev.y * lo.w; acc1 += ev.y * hi.x; acc2 += ev.y * hi.y; acc3 += ev.y * hi.z;
    acc0 += ev.z * lo.z; acc1 += ev.z * lo.w; acc2 += ev.z * hi.x; acc3 += ev.z * hi.y;
    acc0 += ev.w * lo.y; acc1 += ev.w * lo.z; acc2 += ev.w * lo.w; acc3 += ev.w * hi.x;
    hi = lo; lo = nlo;
  }
  __shared__ float sred[H][128];
  const float* __restrict__ Zh = Z + h * L;
  sred[h][tsub * 4 + 0] = acc0 / Zh[Lb + 0];
  sred[h][tsub * 4 + 1] = acc1 / Zh[Lb + 1];
  sred[h][tsub * 4 + 2] = acc2 / Zh[Lb + 2];
  sred[h][tsub * 4 + 3] = acc3 / Zh[Lb + 3];
  __syncthreads();
  if (t < 128) {
    float sc = 0.f;
#pragma unroll
    for (int hh = 0; hh < H; ++hh) sc += sred[hh][t];
    partial_s[((size_t)b * 16 + dt) * L + l0 + t] = sc;
  }
}

// ---------------- K6a: scores = sum_dt partial_s; softmax -> p, den ----------------
__global__ __launch_bounds__(256) void k6a_soft(const float* __restrict__ partial_s,
                                                float* __restrict__ p,
                                                float* __restrict__ den) {
  const int b = blockIdx.x;
  const int t = threadIdx.x;
  __shared__ float red[256];
  float sc[8];
  float mx = -3.4e38f;
#pragma unroll
  for (int k = 0; k < 8; ++k) {
    const int l = t + k * 256;
    const int lt = l >> 7;               // wave-uniform per k
    float sm = 0.f;
    for (int dt = 0; dt <= lt; ++dt)
      sm += partial_s[((size_t)b * 16 + dt) * L + l];
    sc[k] = sm;
    if (l < L - 1) mx = fmaxf(mx, sm);
  }
  red[t] = mx;
  __syncthreads();
  for (int off = 128; off > 0; off >>= 1) {
    if (t < off) red[t] = fmaxf(red[t], red[t + off]);
    __syncthreads();
  }
  mx = red[0];
  __syncthreads();
  float sm = 0.f;
#pragma unroll
  for (int k = 0; k < 8; ++k) {
    const int l = t + k * 256;
    float e = (l < L - 1) ? expf(sc[k] - mx) : 0.f;
    p[b * L + l] = e;
    sm += e;
  }
  red[t] = sm;
  __syncthreads();
  for (int off = 128; off > 0; off >>= 1) {
    if (t < off) red[t] += red[t + off];
    __syncthreads();
  }
  if (t == 0) den[b] = red[0];
}

// ---------------- K6b: partial[b,c,s] = sum_{l in chunk c} p[b,l] * x[b,l,s] ----------------
__global__ __launch_bounds__(256) void k6b_wsum(const float* __restrict__ x,
                                                const float* __restrict__ p,
                                                float* __restrict__ partial) {
  const int b = blockIdx.x, c = blockIdx.y;
  const int t = threadIdx.x;
  const int s4 = t & 31;
  const int r = t >> 5;
  const int base = c * 64;
  const float4* __restrict__ x4 = (const float4*)(x + (size_t)b * L * S);
  const float* __restrict__ pb = p + b * L;
  float4 acc = make_float4(0.f, 0.f, 0.f, 0.f);
#pragma unroll
  for (int k = 0; k < 8; ++k) {
    const int l = base + r + k * 8;
    const float w = pb[l];
    const float4 xv = x4[(size_t)l * 32 + s4];
    acc.x += w * xv.x; acc.y += w * xv.y; acc.z += w * xv.z; acc.w += w * xv.w;
  }
  __shared__ float part[8][S];
  part[r][s4 * 4 + 0] = acc.x;
  part[r][s4 * 4 + 1] = acc.y;
  part[r][s4 * 4 + 2] = acc.z;
  part[r][s4 * 4 + 3] = acc.w;
  __syncthreads();
  if (t < S) {
    float sm = 0.f;
#pragma unroll
    for (int rr = 0; rr < 8; ++rr) sm += part[rr][t];
    partial[((size_t)b * 32 + c) * S + t] = sm;
  }
}

// ---------------- K6c: out[b,s] = sum_c partial[b,c,s] / den[b] ----------------
__global__ __launch_bounds__(128) void k6c_final(const float* __restrict__ partial,
                                                 const float* __restrict__ den,
                                                 float* __restrict__ out) {
  const int b = blockIdx.x;
  const int s = threadIdx.x;
  float sm = 0.f;
#pragma unroll
  for (int c = 0; c < 32; ++c) sm += partial[((size_t)b * 32 + c) * S + s];
  out[b * S + s] = sm / den[b];
}

extern "C" void kernel_launch(void* const* d_in, const int* in_sizes, int n_in,
                              void* d_out, int out_size, void* d_ws, size_t ws_size,
                              hipStream_t stream) {
  const float* x = (const float*)d_in[0];   // (B, L, S) f32
  const float* W = (const float*)d_in[1];   // (L, H)   f32
  const float* A = (const float*)d_in[2];   // (HS, HS) f32
  float* out = (float*)d_out;               // (B, S)   f32

  float* ws        = (float*)d_ws;
  float* E         = ws;                               // H*L        = 16384
  float* Z         = E + H * L;                        // H*L        = 16384
  float* partial_q = Z + H * L;                        // B*32*HS    = 262144
  float* q         = partial_q + (size_t)B * 32 * HS;  // B*HS       = 8192
  float* partial_v = q + B * HS;                       // B*4*HS     = 32768
  float* v         = partial_v + (size_t)B * 4 * HS;   // B*HS       = 8192
  float* u_pad     = v + B * HS;                       // B*H*2L     = 262144
  float* partial_s = u_pad + (size_t)B * H * 2 * L;    // B*16*L     = 262144
  float* p         = partial_s + (size_t)B * 16 * L;   // B*L        = 16384
  float* den       = p + B * L;                        // 64
  float* partial   = den + 64;                         // B*32*S     = 32768
  // total ≈ 917k floats ≈ 3.7 MB of d_ws

  k1_prep  <<<H, 256, 0, stream>>>(W, E, Z);
  k2a_qpart<<<dim3(B, 32),     256, 0, stream>>>(x, E, partial_q);
  k2b_qred <<<B, 256, 0, stream>>>(partial_q, Z, q);
  k3a_vpart<<<dim3(B, 4, 4),   256, 0, stream>>>(q, A, partial_v);
  k3b_vred <<<B, 256, 0, stream>>>(partial_v, v);
  k4_u     <<<dim3(B, 32),     64,  0, stream>>>(x, v, u_pad);
  k5_conv  <<<dim3(B, 16, 16), 256, 0, stream>>>(u_pad, E, Z, partial_s);
  k6a_soft <<<B, 256, 0, stream>>>(partial_s, p, den);
  k6b_wsum <<<dim3(B, 32),     256, 0, stream>>>(x, p, partial);
  k6c_final<<<B, 128, 0, stream>>>(partial, den, out);
}

// Round 4
// 72.302 us; speedup vs baseline: 3.6066x; 1.1161x over previous
//
#include <hip/hip_runtime.h>

#define L 2048
#define H 8
#define S 128
#define B 8
#define HS 1024

// ============ KA: fused {E,Z prefix-scan} + partial_q ============
// grid (B, 32). Every block recomputes its own 64x8 exp(W) slice in LDS.
// Blocks (b==0, jc<8) additionally do the full prefix scan for h=jc -> E,Z.
// partial_q[b,jc,h,s] = sum_{j in chunk jc} E[L-1-j,h] * x[b,j,s]
__global__ __launch_bounds__(256) void kA_prep_qpart(const float* __restrict__ W,
                                                     const float* __restrict__ x,
                                                     float* __restrict__ E,
                                                     float* __restrict__ Z,
                                                     float* __restrict__ partial_q,
                                                     unsigned* __restrict__ counter) {
  const int b = blockIdx.x, jc = blockIdx.y;
  const int t = threadIdx.x;
  if (b == 0 && jc == 0 && t == 0) *counter = 0u;   // reset for kF's last-block gate

  __shared__ float ew[64][H];       // ew[i][h] = E[h, L-1-(base+i)]
  __shared__ float part[8][H][S];   // [r][h][s]
  __shared__ float tot[256];        // scan scratch

  const int base = jc * 64;
  const int dhi = L - 1 - base;
#pragma unroll
  for (int k = 0; k < 2; ++k) {
    const int idx = t + k * 256;    // [0,512): i = idx>>3, h = idx&7
    const int i = idx >> 3, h = idx & 7;
    ew[i][h] = expf(W[(size_t)(dhi - i) * H + h]);
  }

  // --- full prefix scan for one h (8 blocks only) ---
  if (b == 0 && jc < H) {
    const int h = jc;
    const int d0 = t * 8;
    float e[8];
    float run = 0.f;
#pragma unroll
    for (int k = 0; k < 8; ++k) {
      float v = expf(W[(size_t)(d0 + k) * H + h]);
      e[k] = v; run += v;
    }
    tot[t] = run;
    __syncthreads();
    for (int off = 1; off < 256; off <<= 1) {
      float v = (t >= off) ? tot[t - off] : 0.f;
      __syncthreads();
      tot[t] += v;
      __syncthreads();
    }
    float c = (t == 0) ? 0.f : tot[t - 1];
#pragma unroll
    for (int k = 0; k < 8; ++k) {
      c += e[k];
      E[h * L + d0 + k] = e[k];
      Z[h * L + d0 + k] = c;
    }
  }
  __syncthreads();   // ew ready (and scan done)

  // --- partial_q main loop ---
  const int s4 = t & 31;
  const int r = t >> 5;
  const float4* __restrict__ x4 = (const float4*)(x + (size_t)b * L * S);
  float4 acc[H];
#pragma unroll
  for (int h = 0; h < H; ++h) acc[h] = make_float4(0.f, 0.f, 0.f, 0.f);
#pragma unroll
  for (int k = 0; k < 8; ++k) {
    const int ll = k * 8 + r;              // l_local
    const int l = base + ll;
    const float4 xv = x4[(size_t)l * 32 + s4];
#pragma unroll
    for (int h = 0; h < H; ++h) {
      const float w = ew[ll][h];           // LDS broadcast within row-group
      acc[h].x += w * xv.x; acc[h].y += w * xv.y;
      acc[h].z += w * xv.z; acc[h].w += w * xv.w;
    }
  }
#pragma unroll
  for (int h = 0; h < H; ++h) {
    part[r][h][s4 * 4 + 0] = acc[h].x;
    part[r][h][s4 * 4 + 1] = acc[h].y;
    part[r][h][s4 * 4 + 2] = acc[h].z;
    part[r][h][s4 * 4 + 3] = acc[h].w;
  }
  __syncthreads();
#pragma unroll
  for (int k = 0; k < 4; ++k) {
    const int idx = t + k * 256;           // h*S + s
    const int h = idx >> 7, s = idx & 127;
    float sm = 0.f;
#pragma unroll
    for (int rr = 0; rr < 8; ++rr) sm += part[rr][h][s];
    partial_q[((size_t)b * 32 + jc) * HS + idx] = sm;
  }
}

// ============ KB: fused q-reduce + GEMV partial ============
// grid (B, 4, 4): y = e-chunk(256), z = d-chunk(256)
// ql[d] = (sum_jc partial_q[b,jc,d]) / Z[h,L-1];  partial_v[b,dc,e] = sum_d ql[d]*A[d,e]
__global__ __launch_bounds__(256) void kB_v(const float* __restrict__ partial_q,
                                            const float* __restrict__ Z,
                                            const float* __restrict__ A,
                                            float* __restrict__ partial_v) {
  const int b = blockIdx.x;
  const int ebase = blockIdx.y * 256;
  const int dbase = blockIdx.z * 256;
  const int t = threadIdx.x;
  __shared__ float ql[256];
  {
    float acc = 0.f;
    const float* __restrict__ pq = partial_q + (size_t)b * 32 * HS + dbase + t;
#pragma unroll 8
    for (int jc = 0; jc < 32; ++jc) acc += pq[(size_t)jc * HS];
    const int h = (dbase + t) >> 7;
    ql[t] = acc / Z[h * L + (L - 1)];
  }
  __syncthreads();
  const int e = ebase + t;
  float a0 = 0.f, a1 = 0.f, a2 = 0.f, a3 = 0.f;
#pragma unroll 4
  for (int d = 0; d < 256; d += 4) {
    a0 += ql[d    ] * A[(size_t)(dbase + d    ) * HS + e];
    a1 += ql[d + 1] * A[(size_t)(dbase + d + 1) * HS + e];
    a2 += ql[d + 2] * A[(size_t)(dbase + d + 2) * HS + e];
    a3 += ql[d + 3] * A[(size_t)(dbase + d + 3) * HS + e];
  }
  partial_v[((size_t)b * 4 + blockIdx.z) * HS + e] = (a0 + a1) + (a2 + a3);
}

// ============ KC: fused v-reduce + u ============
// grid (B, 32), 256 threads: jl = t&63, sq = t>>6 (4-way s split)
// u[b,h,j] = sum_s v[b,h*S+s]*x[b,j,s]; u_pad front half zeroed
__global__ __launch_bounds__(256) void kC_u(const float* __restrict__ x,
                                            const float* __restrict__ partial_v,
                                            float* __restrict__ u_pad) {
  const int b = blockIdx.x, jc = blockIdx.y;
  const int t = threadIdx.x;
  __shared__ float vs[HS];
  __shared__ float up[4][H][64];
#pragma unroll
  for (int k = 0; k < 4; ++k) {
    const int i = t + k * 256;
    float a = 0.f;
#pragma unroll
    for (int dc = 0; dc < 4; ++dc) a += partial_v[((size_t)b * 4 + dc) * HS + i];
    vs[i] = a;
  }
  __syncthreads();
  const int jl = t & 63, sq = t >> 6;
  const int j = jc * 64 + jl;
  const float4* __restrict__ xr = (const float4*)(x + ((size_t)b * L + j) * S) + sq * 8;
  float4 xv[8];
#pragma unroll
  for (int i = 0; i < 8; ++i) xv[i] = xr[i];
  float acc[H];
#pragma unroll
  for (int h = 0; h < H; ++h) {
    const float4* __restrict__ vv = (const float4*)(vs + h * S + sq * 32);
    float a = 0.f;
#pragma unroll
    for (int i = 0; i < 8; ++i) {
      const float4 w = vv[i];   // same addr across wave -> LDS broadcast
      a += xv[i].x * w.x + xv[i].y * w.y + xv[i].z * w.z + xv[i].w * w.w;
    }
    acc[h] = a;
  }
#pragma unroll
  for (int h = 0; h < H; ++h) up[sq][h][jl] = acc[h];
  __syncthreads();
#pragma unroll
  for (int k = 0; k < 2; ++k) {
    const int idx = t + k * 256;       // [0,512): h = idx>>6, j2 = idx&63
    const int h = idx >> 6, j2 = idx & 63;
    const float s = up[0][h][j2] + up[1][h][j2] + up[2][h][j2] + up[3][h][j2];
    const size_t rowbase = (size_t)(b * H + h) * (2 * L);
    u_pad[rowbase + jc * 64 + j2] = 0.f;        // zero pad (front half)
    u_pad[rowbase + L + jc * 64 + j2] = s;
  }
}

// ============ KD: conv partials over 128x128 (l,d) tiles ============
__global__ __launch_bounds__(256) void kD_conv(const float* __restrict__ u_pad,
                                               const float* __restrict__ E,
                                               const float* __restrict__ Z,
                                               float* __restrict__ partial_s) {
  const int lt = blockIdx.y, dt = blockIdx.z;
  if (dt > lt) return;
  const int b = blockIdx.x;
  const int l0 = lt * 128;
  const int dbase = dt * 128;
  const int t = threadIdx.x;
  const int tsub = t & 31;
  const int h = t >> 5;
  const int Lb = l0 + tsub * 4;
  const float* __restrict__ ur = u_pad + (size_t)(b * H + h) * (2 * L) + L;
  const float4* __restrict__ Eh4 = (const float4*)(E + h * L);
  float acc0 = 0.f, acc1 = 0.f, acc2 = 0.f, acc3 = 0.f;
  float4 lo = *(const float4*)(ur + Lb - dbase - 4);
  float4 hi = *(const float4*)(ur + Lb - dbase);
#pragma unroll 4
  for (int dd = 0; dd < 128; dd += 4) {
    const int d0 = dbase + dd;
    float4 ev  = Eh4[d0 >> 2];
    float4 nlo = *(const float4*)(ur + Lb - d0 - 8);
    acc0 += ev.x * hi.x; acc1 += ev.x * hi.y; acc2 += ev.x * hi.z; acc3 += ev.x * hi.w;
    acc0 += ev.y * lo.w; acc1 += ev.y * hi.x; acc2 += ev.y * hi.y; acc3 += ev.y * hi.z;
    acc0 += ev.z * lo.z; acc1 += ev.z * lo.w; acc2 += ev.z * hi.x; acc3 += ev.z * hi.y;
    acc0 += ev.w * lo.y; acc1 += ev.w * lo.z; acc2 += ev.w * lo.w; acc3 += ev.w * hi.x;
    hi = lo; lo = nlo;
  }
  __shared__ float sred[H][128];
  const float* __restrict__ Zh = Z + h * L;
  sred[h][tsub * 4 + 0] = acc0 / Zh[Lb + 0];
  sred[h][tsub * 4 + 1] = acc1 / Zh[Lb + 1];
  sred[h][tsub * 4 + 2] = acc2 / Zh[Lb + 2];
  sred[h][tsub * 4 + 3] = acc3 / Zh[Lb + 3];
  __syncthreads();
  if (t < 128) {
    float sc = 0.f;
#pragma unroll
    for (int hh = 0; hh < H; ++hh) sc += sred[hh][t];
    partial_s[((size_t)b * 16 + dt) * L + l0 + t] = sc;
  }
}

// ============ KE: score reduce + softmax -> normalized p ============
// grid (B); thread t owns l in [8t, 8t+8)
__global__ __launch_bounds__(256) void kE_soft(const float* __restrict__ partial_s,
                                               float* __restrict__ p) {
  const int b = blockIdx.x;
  const int t = threadIdx.x;
  __shared__ float red[256];
  const int l0 = t * 8;
  const int lt = t >> 4;                 // (8t)>>7
  float sc[8];
#pragma unroll
  for (int k = 0; k < 8; ++k) sc[k] = 0.f;
  for (int dt = 0; dt <= lt; ++dt) {
    const float4* __restrict__ ps = (const float4*)(partial_s + ((size_t)b * 16 + dt) * L + l0);
    const float4 a = ps[0], c = ps[1];
    sc[0] += a.x; sc[1] += a.y; sc[2] += a.z; sc[3] += a.w;
    sc[4] += c.x; sc[5] += c.y; sc[6] += c.z; sc[7] += c.w;
  }
  if (t == 255) sc[7] = -3.4e38f;        // l = 2047 excluded
  float mx = sc[0];
#pragma unroll
  for (int k = 1; k < 8; ++k) mx = fmaxf(mx, sc[k]);
  red[t] = mx;
  __syncthreads();
  for (int off = 128; off > 0; off >>= 1) {
    if (t < off) red[t] = fmaxf(red[t], red[t + off]);
    __syncthreads();
  }
  mx = red[0];
  __syncthreads();
  float e[8];
  float sm = 0.f;
#pragma unroll
  for (int k = 0; k < 8; ++k) {
    e[k] = (l0 + k < L - 1) ? expf(sc[k] - mx) : 0.f;
    sm += e[k];
  }
  red[t] = sm;
  __syncthreads();
  for (int off = 128; off > 0; off >>= 1) {
    if (t < off) red[t] += red[t + off];
    __syncthreads();
  }
  const float inv = 1.f / red[0];
  float4* __restrict__ pp = (float4*)(p + (size_t)b * L + l0);
  pp[0] = make_float4(e[0] * inv, e[1] * inv, e[2] * inv, e[3] * inv);
  pp[1] = make_float4(e[4] * inv, e[5] * inv, e[6] * inv, e[7] * inv);
}

// ============ KF: weighted sum partials + last-block final reduce ============
// grid (B, 32); last finishing block sums all partials in fixed order (deterministic)
__global__ __launch_bounds__(256) void kF_out(const float* __restrict__ x,
                                              const float* __restrict__ p,
                                              float* __restrict__ partial,
                                              unsigned* __restrict__ counter,
                                              float* __restrict__ out) {
  const int b = blockIdx.x, c = blockIdx.y;
  const int t = threadIdx.x;
  const int s4 = t & 31;
  const int r = t >> 5;
  const int base = c * 64;
  const float4* __restrict__ x4 = (const float4*)(x + (size_t)b * L * S);
  const float* __restrict__ pb = p + (size_t)b * L;
  float4 acc = make_float4(0.f, 0.f, 0.f, 0.f);
#pragma unroll
  for (int k = 0; k < 8; ++k) {
    const int l = base + r + k * 8;
    const float w = pb[l];
    const float4 xv = x4[(size_t)l * 32 + s4];
    acc.x += w * xv.x; acc.y += w * xv.y; acc.z += w * xv.z; acc.w += w * xv.w;
  }
  __shared__ float part[8][S];
  part[r][s4 * 4 + 0] = acc.x;
  part[r][s4 * 4 + 1] = acc.y;
  part[r][s4 * 4 + 2] = acc.z;
  part[r][s4 * 4 + 3] = acc.w;
  __syncthreads();
  if (t < S) {
    float sm = 0.f;
#pragma unroll
    for (int rr = 0; rr < 8; ++rr) sm += part[rr][t];
    partial[((size_t)b * 32 + c) * S + t] = sm;
  }
  // --- last-block gate ---
  __threadfence();                 // all threads: make partial visible device-wide
  __syncthreads();
  __shared__ unsigned lastFlag;
  if (t == 0) {
    const unsigned old = atomicAdd(counter, 1u);
    lastFlag = (old == (unsigned)(B * 32 - 1)) ? 1u : 0u;
  }
  __syncthreads();
  if (lastFlag) {
#pragma unroll
    for (int k = 0; k < 4; ++k) {
      const int idx = t + k * 256;   // b2 = idx>>7, s = idx&127
      const int b2 = idx >> 7, s = idx & 127;
      float a = 0.f;
      for (int cc = 0; cc < 32; ++cc) a += partial[((size_t)b2 * 32 + cc) * S + s];
      out[b2 * S + s] = a;
    }
  }
}

extern "C" void kernel_launch(void* const* d_in, const int* in_sizes, int n_in,
                              void* d_out, int out_size, void* d_ws, size_t ws_size,
                              hipStream_t stream) {
  const float* x = (const float*)d_in[0];   // (B, L, S) f32
  const float* W = (const float*)d_in[1];   // (L, H)   f32
  const float* A = (const float*)d_in[2];   // (HS, HS) f32
  float* out = (float*)d_out;               // (B, S)   f32

  float* ws        = (float*)d_ws;
  float* E         = ws;                               // H*L     = 16384
  float* Z         = E + H * L;                        // H*L     = 16384
  float* partial_q = Z + H * L;                        // B*32*HS = 262144
  float* partial_v = partial_q + (size_t)B * 32 * HS;  // B*4*HS  = 32768
  float* u_pad     = partial_v + (size_t)B * 4 * HS;   // B*H*2L  = 262144
  float* partial_s = u_pad + (size_t)B * H * 2 * L;    // B*16*L  = 262144
  float* p         = partial_s + (size_t)B * 16 * L;   // B*L     = 16384
  float* partial   = p + B * L;                        // B*32*S  = 32768
  unsigned* counter = (unsigned*)(partial + (size_t)B * 32 * S);
  // total ≈ 3.5 MB of d_ws

  kA_prep_qpart<<<dim3(B, 32),     256, 0, stream>>>(W, x, E, Z, partial_q, counter);
  kB_v         <<<dim3(B, 4, 4),   256, 0, stream>>>(partial_q, Z, A, partial_v);
  kC_u         <<<dim3(B, 32),     256, 0, stream>>>(x, partial_v, u_pad);
  kD_conv      <<<dim3(B, 16, 16), 256, 0, stream>>>(u_pad, E, Z, partial_s);
  kE_soft      <<<B, 256, 0, stream>>>(partial_s, p);
  kF_out       <<<dim3(B, 32),     256, 0, stream>>>(x, p, partial, counter, out);
}